// Round 7
// baseline (359.797 us; speedup 1.0000x reference)
//
#include <hip/hip_runtime.h>
#include <math.h>

#define LN_EPS 1e-5f

typedef __attribute__((ext_vector_type(8))) __bf16 bf16x8;
typedef __attribute__((ext_vector_type(4))) float f32x4;

__device__ inline float bf2f(unsigned short u) {
  union { unsigned int i; float f; } x; x.i = ((unsigned int)u) << 16; return x.f;
}
__device__ inline unsigned short f2bf(float f) {
  union { float f; unsigned int i; } x; x.f = f;
  unsigned int r = (x.i + 0x7FFFu + ((x.i >> 16) & 1u)) >> 16;   // RNE
  return (unsigned short)r;
}
__device__ inline void gload_lds16(const void* g, void* l) {
  __builtin_amdgcn_global_load_lds((const __attribute__((address_space(1))) void*)g,
                                   (__attribute__((address_space(3))) void*)l, 16, 0, 0);
}

// ---------------- f32 -> bf16 elementwise ----------------
__global__ __launch_bounds__(256)
void to_bf16(const float* __restrict__ in, unsigned short* __restrict__ outp, long n) {
  long i = ((long)blockIdx.x * 256 + threadIdx.x) * 4;
  if (i >= n) return;
  float4 v = *(const float4*)&in[i];
  ushort4 o = { f2bf(v.x), f2bf(v.y), f2bf(v.z), f2bf(v.w) };
  *(ushort4*)&outp[i] = o;
}

// ---------------- W[K,M] f32 -> Wt[M,K] bf16 ----------------
__global__ __launch_bounds__(256)
void transpose_w(const float* __restrict__ W, unsigned short* __restrict__ Wt, int K, int M) {
  __shared__ float t[32][33];
  const int k0 = blockIdx.x * 32, m0 = blockIdx.y * 32;
  const int tx = threadIdx.x & 31, ty = threadIdx.x >> 5;  // 32 x 8
#pragma unroll
  for (int i = 0; i < 32; i += 8)
    t[ty + i][tx] = W[(size_t)(k0 + ty + i) * M + m0 + tx];
  __syncthreads();
#pragma unroll
  for (int i = 0; i < 32; i += 8)
    Wt[(size_t)(m0 + ty + i) * K + k0 + tx] = f2bf(t[tx][ty + i]);
}

// ---------------- concat 3 x 128 bias -> 384 ----------------
__global__ __launch_bounds__(384)
void concat_bias3(const float* __restrict__ a, const float* __restrict__ b,
                  const float* __restrict__ c, float* __restrict__ o) {
  int t = threadIdx.x;
  o[t] = t < 128 ? a[t] : (t < 256 ? b[t - 128] : c[t - 256]);
}

// ---------------- bf16 MFMA GEMM: C[N,M] = A[N,K] @ Wt[M,K]^T + bias ----------------
template<bool OBF>
__global__ __launch_bounds__(256)
void gemm_mfma(const unsigned short* __restrict__ A, const unsigned short* __restrict__ Wt,
               const float* __restrict__ bias, void* __restrict__ Cout,
               int Nr, int K, int M) {
  __shared__ __align__(16) unsigned short As[128 * 64];
  __shared__ __align__(16) unsigned short Bs[128 * 64];
  const int tid = threadIdx.x;
  const int bm = blockIdx.x * 128, bn = blockIdx.y * 128;
  const int lane = tid & 63;
  const int wr = (tid >> 6) >> 1, wc = (tid >> 6) & 1;
  f32x4 acc[4][4] = {};
  const int nkt = K >> 6;
  for (int kt = 0; kt < nkt; ++kt) {
#pragma unroll
    for (int i = 0; i < 4; ++i) {
      int c = tid + i * 256;
      int row = c >> 3;
      int j = (c & 7) ^ (row & 7);
      int ar = bm + row; ar = ar < Nr ? ar : Nr - 1;
      gload_lds16(A + (size_t)ar * K + kt * 64 + j * 8, As + (size_t)c * 8);
      gload_lds16(Wt + (size_t)(bn + row) * K + kt * 64 + j * 8, Bs + (size_t)c * 8);
    }
    __syncthreads();
#pragma unroll
    for (int ks = 0; ks < 2; ++ks) {
      bf16x8 af[4], bfr[4];
#pragma unroll
      for (int f = 0; f < 4; ++f) {
        int rowa = wr * 64 + f * 16 + (lane & 15);
        int ja = (ks * 4 + (lane >> 4)) ^ (rowa & 7);
        af[f] = *(const bf16x8*)(As + rowa * 64 + ja * 8);
        int rowb = wc * 64 + f * 16 + (lane & 15);
        int jb = (ks * 4 + (lane >> 4)) ^ (rowb & 7);
        bfr[f] = *(const bf16x8*)(Bs + rowb * 64 + jb * 8);
      }
#pragma unroll
      for (int fr = 0; fr < 4; ++fr)
#pragma unroll
        for (int fc = 0; fc < 4; ++fc)
          acc[fr][fc] = __builtin_amdgcn_mfma_f32_16x16x32_bf16(af[fr], bfr[fc], acc[fr][fc], 0, 0, 0);
    }
    __syncthreads();
  }
#pragma unroll
  for (int fr = 0; fr < 4; ++fr) {
#pragma unroll
    for (int j = 0; j < 4; ++j) {
      int row = bm + wr * 64 + fr * 16 + (lane >> 4) * 4 + j;
      if (row < Nr) {
#pragma unroll
        for (int fc = 0; fc < 4; ++fc) {
          int col = bn + wc * 64 + fc * 16 + (lane & 15);
          float v = acc[fr][fc][j] + bias[col];
          if (OBF) ((unsigned short*)Cout)[(size_t)row * M + col] = f2bf(v);
          else     ((float*)Cout)[(size_t)row * M + col] = v;
        }
      }
    }
  }
}

// ---------------- bf16 MFMA GEMM (M=128) fused with y = LN(res + A@Wt^T + bias) ----------------
template<bool WBF>
__global__ __launch_bounds__(256)
void gemm_ln(const unsigned short* __restrict__ A, const unsigned short* __restrict__ Wt,
             const float* __restrict__ bias, const float* __restrict__ res,
             const float* __restrict__ g, const float* __restrict__ b,
             float* __restrict__ y, unsigned short* __restrict__ ybf, int Nr, int K) {
  __shared__ __align__(16) unsigned short As[128 * 64];
  __shared__ __align__(16) unsigned short Bs[128 * 64];
  __shared__ float pls[128][2], plss[128][2];
  const int tid = threadIdx.x;
  const int bm = blockIdx.x * 128;
  const int lane = tid & 63;
  const int wr = (tid >> 6) >> 1, wc = (tid >> 6) & 1;
  f32x4 acc[4][4] = {};
  const int nkt = K >> 6;
  for (int kt = 0; kt < nkt; ++kt) {
#pragma unroll
    for (int i = 0; i < 4; ++i) {
      int c = tid + i * 256;
      int row = c >> 3;
      int j = (c & 7) ^ (row & 7);
      int ar = bm + row; ar = ar < Nr ? ar : Nr - 1;
      gload_lds16(A + (size_t)ar * K + kt * 64 + j * 8, As + (size_t)c * 8);
      gload_lds16(Wt + (size_t)row * K + kt * 64 + j * 8, Bs + (size_t)c * 8);
    }
    __syncthreads();
#pragma unroll
    for (int ks = 0; ks < 2; ++ks) {
      bf16x8 af[4], bfr[4];
#pragma unroll
      for (int f = 0; f < 4; ++f) {
        int rowa = wr * 64 + f * 16 + (lane & 15);
        int ja = (ks * 4 + (lane >> 4)) ^ (rowa & 7);
        af[f] = *(const bf16x8*)(As + rowa * 64 + ja * 8);
        int rowb = wc * 64 + f * 16 + (lane & 15);
        int jb = (ks * 4 + (lane >> 4)) ^ (rowb & 7);
        bfr[f] = *(const bf16x8*)(Bs + rowb * 64 + jb * 8);
      }
#pragma unroll
      for (int fr = 0; fr < 4; ++fr)
#pragma unroll
        for (int fc = 0; fc < 4; ++fc)
          acc[fr][fc] = __builtin_amdgcn_mfma_f32_16x16x32_bf16(af[fr], bfr[fc], acc[fr][fc], 0, 0, 0);
    }
    __syncthreads();
  }
  // epilogue: val = acc + bias + res; per-row LN across both wc halves via LDS partials
#pragma unroll
  for (int fr = 0; fr < 4; ++fr) {
#pragma unroll
    for (int j = 0; j < 4; ++j) {
      const int rl = wr * 64 + fr * 16 + (lane >> 4) * 4 + j;
      const int row = bm + rl;
      const int rowc = row < Nr ? row : Nr - 1;
      float s = 0.f, ss = 0.f;
#pragma unroll
      for (int fc = 0; fc < 4; ++fc) {
        int col = wc * 64 + fc * 16 + (lane & 15);
        float val = acc[fr][fc][j] + bias[col] + res[(size_t)rowc * 128 + col];
        acc[fr][fc][j] = val;
        s += val; ss += val * val;
      }
      s += __shfl_xor(s, 1); ss += __shfl_xor(ss, 1);
      s += __shfl_xor(s, 2); ss += __shfl_xor(ss, 2);
      s += __shfl_xor(s, 4); ss += __shfl_xor(ss, 4);
      s += __shfl_xor(s, 8); ss += __shfl_xor(ss, 8);
      if ((lane & 15) == 0) { pls[rl][wc] = s; plss[rl][wc] = ss; }
    }
  }
  __syncthreads();
#pragma unroll
  for (int fr = 0; fr < 4; ++fr) {
#pragma unroll
    for (int j = 0; j < 4; ++j) {
      const int rl = wr * 64 + fr * 16 + (lane >> 4) * 4 + j;
      const int row = bm + rl;
      if (row >= Nr) continue;
      const float S = pls[rl][0] + pls[rl][1];
      const float SS = plss[rl][0] + plss[rl][1];
      const float mu = S * (1.f / 128.f);
      const float inv = rsqrtf(SS * (1.f / 128.f) - mu * mu + LN_EPS);
#pragma unroll
      for (int fc = 0; fc < 4; ++fc) {
        int col = wc * 64 + fc * 16 + (lane & 15);
        float o = (acc[fr][fc][j] - mu) * inv * g[col] + b[col];
        y[(size_t)row * 128 + col] = o;
        if (WBF) ybf[(size_t)row * 128 + col] = f2bf(o);
      }
    }
  }
}

// ---------------- CSR build ----------------
__global__ __launch_bounds__(256)
void edge_hist(const int* __restrict__ ei, int* __restrict__ deg, int E) {
  int e = blockIdx.x * 256 + threadIdx.x;
  if (e < E) atomicAdd(&deg[ei[E + e]], 1);
}

__global__ __launch_bounds__(256)
void deg_block_sum(const int* __restrict__ deg, int* __restrict__ bsum, int N) {
  const int t = threadIdx.x;
  const int beg = blockIdx.x * 2048 + t * 8;
  int s = 0;
#pragma unroll
  for (int j = 0; j < 8; ++j) { int i = beg + j; if (i < N) s += deg[i]; }
#pragma unroll
  for (int off = 32; off; off >>= 1) s += __shfl_xor(s, off);
  __shared__ int ws[4];
  if ((t & 63) == 0) ws[t >> 6] = s;
  __syncthreads();
  if (t == 0) bsum[blockIdx.x] = ws[0] + ws[1] + ws[2] + ws[3];
}

__global__ __launch_bounds__(64)
void scan_bsum(int* __restrict__ bsum, int* __restrict__ offs_last, int nb) {
  const int t = threadIdx.x;
  int v = (t < nb) ? bsum[t] : 0;
  int inc = v;
#pragma unroll
  for (int off = 1; off < 64; off <<= 1) {
    int x = __shfl_up(inc, off);
    if (t >= off) inc += x;
  }
  if (t < nb) bsum[t] = inc - v;
  if (t == 63) *offs_last = inc;
}

__global__ __launch_bounds__(256)
void deg_scan_write(const int* __restrict__ deg, const int* __restrict__ bsum,
                    int* __restrict__ offs, int* __restrict__ pos, int N) {
  const int t = threadIdx.x;
  const int beg = blockIdx.x * 2048 + t * 8;
  int loc[8]; int T = 0;
#pragma unroll
  for (int j = 0; j < 8; ++j) { int i = beg + j; loc[j] = (i < N) ? deg[i] : 0; T += loc[j]; }
  int inc = T;
#pragma unroll
  for (int off = 1; off < 64; off <<= 1) {
    int x = __shfl_up(inc, off);
    if ((t & 63) >= off) inc += x;
  }
  __shared__ int ws[4];
  if ((t & 63) == 63) ws[t >> 6] = inc;
  __syncthreads();
  const int wid = t >> 6;
  int wbase = 0;
  for (int w = 0; w < wid; ++w) wbase += ws[w];
  int base = bsum[blockIdx.x] + wbase + inc - T;
#pragma unroll
  for (int j = 0; j < 8; ++j) {
    int i = beg + j;
    if (i < N) { offs[i] = base; pos[i] = base; base += loc[j]; }
  }
}

// rank pass: only scattered write is 4B inv[p] = e
__global__ __launch_bounds__(256)
void edge_rank(const int* __restrict__ ei, int* __restrict__ pos,
               int* __restrict__ inv, int E) {
  int e = blockIdx.x * 256 + threadIdx.x;
  if (e < E) {
    int d = ei[E + e];
    int p = atomicAdd(&pos[d], 1);
    inv[p] = e;
  }
}

// fill pass: sequential in p; gathers ea row (line-aligned 128B), coalesced writes
__global__ __launch_bounds__(256)
void csr_fill(const int* __restrict__ inv, const int* __restrict__ ei,
              const float* __restrict__ ea, const float* __restrict__ eW,
              const float* __restrict__ eb, int* __restrict__ csr_src,
              unsigned short* __restrict__ ebp, int E) {
  __shared__ float ews[256];
  __shared__ float ebs[8];
  const int tid = threadIdx.x;
  if (tid < 256) ews[tid] = eW[tid];
  if (tid < 8) ebs[tid] = eb[tid];
  __syncthreads();
  int p = blockIdx.x * 256 + tid;
  if (p >= E) return;
  const int e = inv[p];
  float bias[8];
#pragma unroll
  for (int h = 0; h < 8; ++h) bias[h] = ebs[h];
#pragma unroll
  for (int i4 = 0; i4 < 8; ++i4) {
    float4 a = *(const float4*)&ea[(size_t)e * 32 + i4 * 4];
    float av[4] = {a.x, a.y, a.z, a.w};
#pragma unroll
    for (int j = 0; j < 4; ++j)
#pragma unroll
      for (int h = 0; h < 8; ++h) bias[h] += av[j] * ews[(i4 * 4 + j) * 8 + h];
  }
  csr_src[p] = ei[e];
  union { unsigned short us[8]; uint4 v; } pk;
#pragma unroll
  for (int h = 0; h < 8; ++h) pk.us[h] = f2bf(bias[h]);
  *(uint4*)&ebp[(size_t)p * 8] = pk.v;
}

// ---------------- fused per-node attention aggregate ----------------
// merged qkv[N][384] bf16 (q:0-127, k:128-255, v:256-383); one wave per node (static)
__global__ __launch_bounds__(256)
void node_agg(const int* __restrict__ csr_src, const int* __restrict__ offs,
              const unsigned short* __restrict__ qkv, const unsigned short* __restrict__ ebp,
              unsigned short* __restrict__ agg, int N) {
  const int wid = threadIdx.x >> 6, lane = threadIdx.x & 63;
  const int h = lane >> 3;
  const long n = (long)blockIdx.x * 4 + wid;
  if (n >= N) return;
  const int off = offs[n], end = offs[n + 1];
  const ushort2 kv2 = *(const ushort2*)&qkv[(size_t)n * 384 + 128 + lane * 2];
  const float k0 = bf2f(kv2.x), k1 = bf2f(kv2.y);
  float acc0 = 0.f, acc1 = 0.f, den = 0.f;
  int i = off;
  for (; i + 4 <= end; i += 4) {       // 4-wide: 8 independent q/v gathers in flight
    const size_t b0 = (size_t)csr_src[i] * 384;
    const size_t b1 = (size_t)csr_src[i + 1] * 384;
    const size_t b2 = (size_t)csr_src[i + 2] * 384;
    const size_t b3 = (size_t)csr_src[i + 3] * 384;
    const ushort2 qa = *(const ushort2*)&qkv[b0 + lane * 2];
    const ushort2 qb = *(const ushort2*)&qkv[b1 + lane * 2];
    const ushort2 qc = *(const ushort2*)&qkv[b2 + lane * 2];
    const ushort2 qd = *(const ushort2*)&qkv[b3 + lane * 2];
    const ushort2 va = *(const ushort2*)&qkv[b0 + 256 + lane * 2];
    const ushort2 vb = *(const ushort2*)&qkv[b1 + 256 + lane * 2];
    const ushort2 vc = *(const ushort2*)&qkv[b2 + 256 + lane * 2];
    const ushort2 vd = *(const ushort2*)&qkv[b3 + 256 + lane * 2];
    const float e0 = bf2f(ebp[(size_t)i * 8 + h]);
    const float e1 = bf2f(ebp[(size_t)(i + 1) * 8 + h]);
    const float e2 = bf2f(ebp[(size_t)(i + 2) * 8 + h]);
    const float e3 = bf2f(ebp[(size_t)(i + 3) * 8 + h]);
    float p0 = bf2f(qa.x) * k0 + bf2f(qa.y) * k1;
    float p1 = bf2f(qb.x) * k0 + bf2f(qb.y) * k1;
    float p2 = bf2f(qc.x) * k0 + bf2f(qc.y) * k1;
    float p3 = bf2f(qd.x) * k0 + bf2f(qd.y) * k1;
    p0 += __shfl_xor(p0, 1); p1 += __shfl_xor(p1, 1); p2 += __shfl_xor(p2, 1); p3 += __shfl_xor(p3, 1);
    p0 += __shfl_xor(p0, 2); p1 += __shfl_xor(p1, 2); p2 += __shfl_xor(p2, 2); p3 += __shfl_xor(p3, 2);
    p0 += __shfl_xor(p0, 4); p1 += __shfl_xor(p1, 4); p2 += __shfl_xor(p2, 4); p3 += __shfl_xor(p3, 4);
    const float x0 = __expf(p0 * 0.25f + e0);
    const float x1 = __expf(p1 * 0.25f + e1);
    const float x2 = __expf(p2 * 0.25f + e2);
    const float x3 = __expf(p3 * 0.25f + e3);
    den += (x0 + x1) + (x2 + x3);
    acc0 += bf2f(va.x) * x0 + bf2f(vb.x) * x1 + bf2f(vc.x) * x2 + bf2f(vd.x) * x3;
    acc1 += bf2f(va.y) * x0 + bf2f(vb.y) * x1 + bf2f(vc.y) * x2 + bf2f(vd.y) * x3;
  }
  for (; i < end; ++i) {
    const size_t b0 = (size_t)csr_src[i] * 384;
    const ushort2 qa = *(const ushort2*)&qkv[b0 + lane * 2];
    const ushort2 va = *(const ushort2*)&qkv[b0 + 256 + lane * 2];
    float p = bf2f(qa.x) * k0 + bf2f(qa.y) * k1;
    p += __shfl_xor(p, 1);
    p += __shfl_xor(p, 2);
    p += __shfl_xor(p, 4);
    const float ex = __expf(p * 0.25f + bf2f(ebp[(size_t)i * 8 + h]));
    den += ex;
    acc0 += bf2f(va.x) * ex;
    acc1 += bf2f(va.y) * ex;
  }
  const float r = 1.f / fmaxf(den, 1e-8f);
  ushort2 o; o.x = f2bf(acc0 * r); o.y = f2bf(acc1 * r);
  *(ushort2*)&agg[(size_t)n * 128 + lane * 2] = o;
}

// ---------------- in-place LN(row of 512) -> exact GELU, bf16 ----------------
__global__ __launch_bounds__(256)
void ln_gelu512(unsigned short* __restrict__ hbuf, const float* __restrict__ g,
                const float* __restrict__ b, int Nr) {
  __shared__ float rs[4], rss[4];
  const long row = blockIdx.x;
  const int tid = threadIdx.x;
  ushort2 u = *(ushort2*)&hbuf[row * 512 + tid * 2];
  float v0 = bf2f(u.x), v1 = bf2f(u.y);
  float s = v0 + v1, ss = v0 * v0 + v1 * v1;
#pragma unroll
  for (int off = 32; off; off >>= 1) { s += __shfl_xor(s, off); ss += __shfl_xor(ss, off); }
  const int wid = tid >> 6, lane = tid & 63;
  if (lane == 0) { rs[wid] = s; rss[wid] = ss; }
  __syncthreads();
  s = rs[0] + rs[1] + rs[2] + rs[3];
  ss = rss[0] + rss[1] + rss[2] + rss[3];
  const float mu = s * (1.f / 512.f);
  const float inv = rsqrtf(ss * (1.f / 512.f) - mu * mu + LN_EPS);
  float t0 = (v0 - mu) * inv * g[tid * 2] + b[tid * 2];
  float t1 = (v1 - mu) * inv * g[tid * 2 + 1] + b[tid * 2 + 1];
  t0 = 0.5f * t0 * (1.f + erff(t0 * 0.70710678118654752f));
  t1 = 0.5f * t1 * (1.f + erff(t1 * 0.70710678118654752f));
  ushort2 o; o.x = f2bf(t0); o.y = f2bf(t1);
  *(ushort2*)&hbuf[row * 512 + tid * 2] = o;
}

extern "C" void kernel_launch(void* const* d_in, const int* in_sizes, int n_in,
                              void* d_out, int out_size, void* d_ws, size_t ws_size,
                              hipStream_t stream) {
  const float* x   = (const float*)d_in[0];
  const int*   ei  = (const int*)d_in[1];
  const float* ea  = (const float*)d_in[2];
  const float* qW  = (const float*)d_in[3];
  const float* qbi = (const float*)d_in[4];
  const float* kW  = (const float*)d_in[5];
  const float* kbi = (const float*)d_in[6];
  const float* vW  = (const float*)d_in[7];
  const float* vbi = (const float*)d_in[8];
  const float* eW  = (const float*)d_in[9];
  const float* eb  = (const float*)d_in[10];
  const float* oW  = (const float*)d_in[11];
  const float* ob  = (const float*)d_in[12];
  const float* ln1_g = (const float*)d_in[13];
  const float* ln1_b = (const float*)d_in[14];
  const float* f1W = (const float*)d_in[15];
  const float* f1b = (const float*)d_in[16];
  const float* lnf_g = (const float*)d_in[17];
  const float* lnf_b = (const float*)d_in[18];
  const float* f2W = (const float*)d_in[19];
  const float* f2b = (const float*)d_in[20];
  const float* ln2_g = (const float*)d_in[21];
  const float* ln2_b = (const float*)d_in[22];
  float* out = (float*)d_out;

  const int N = in_sizes[0] / 128;
  const int E = in_sizes[1] / 2;
  const size_t NH = (size_t)N * 128;   // 6.4M floats

  // workspace (float units), lifetime-overlapped, peak ~4.3*NH (~110 MB):
  //  [0, .5NH)      xbf bf16  -> x1bf bf16 (after QKV gemm)
  //  [.5NH, 2NH)    qkv bf16 [N][384]  \__ hbuf bf16 [N][512] overlays [.5NH, 2.5NH)
  //  [2NH, 2.5NH)   ebp bf16 [E][8]    /    (qkv+ebp dead before f1 writes hbuf)
  //  [2.5NH, 3NH)   aggb bf16
  //  [3NH, 4NH)     x1 f32
  //  [4NH, ...)     ints: csr_src E, offs N+1, pos N, bsum, inv E; then bf16 weights + bias
  float* F = (float*)d_ws;
  unsigned short* xbf   = (unsigned short*)F;
  unsigned short* qkvb  = (unsigned short*)(F + NH / 2);
  unsigned short* ebp   = (unsigned short*)(F + 2 * NH);
  unsigned short* aggb  = (unsigned short*)(F + 2 * NH + NH / 2);
  float*          x1    = F + 3 * NH;
  unsigned short* x1bf  = xbf;
  unsigned short* hbufb = (unsigned short*)(F + NH / 2);
  int* ib      = (int*)(F + 4 * NH);
  int* csr_src = ib;
  int* offs    = ib + E;
  int* pos     = ib + E + N + 1;
  int* bsum    = ib + E + 2 * N + 1;
  int* inv     = ib + E + 2 * N + 128;
  unsigned short* wt = (unsigned short*)(inv + E);
  unsigned short* qkvWt = wt;            // 384x128
  unsigned short* oWt   = wt + 49152;    // 128x128
  unsigned short* f1Wt  = wt + 65536;    // 512x128
  unsigned short* f2Wt  = wt + 131072;   // 128x512
  float* qkvbias = (float*)(wt + 196608);

  dim3 blk(256);
  dim3 gqkv((N + 127) / 128, 3);
  dim3 g128((N + 127) / 128, 1);
  dim3 gf1((N + 127) / 128, 4);
  const int nb = (N + 2047) / 2048;
  const int ge = (E + 255) / 256;

  // converts + weight transposes + merged bias
  to_bf16<<<dim3((int)((NH / 4 + 255) / 256)), blk, 0, stream>>>(x, xbf, (long)NH);
  transpose_w<<<dim3(4, 4), blk, 0, stream>>>(qW, qkvWt, 128, 128);
  transpose_w<<<dim3(4, 4), blk, 0, stream>>>(kW, qkvWt + 16384, 128, 128);
  transpose_w<<<dim3(4, 4), blk, 0, stream>>>(vW, qkvWt + 32768, 128, 128);
  transpose_w<<<dim3(4, 4), blk, 0, stream>>>(oW, oWt, 128, 128);
  transpose_w<<<dim3(4, 16), blk, 0, stream>>>(f1W, f1Wt, 128, 512);
  transpose_w<<<dim3(16, 4), blk, 0, stream>>>(f2W, f2Wt, 512, 128);
  concat_bias3<<<dim3(1), dim3(384), 0, stream>>>(qbi, kbi, vbi, qkvbias);

  // merged QKV projection -> qkv[N][384] bf16
  gemm_mfma<true><<<gqkv, blk, 0, stream>>>(xbf, qkvWt, qkvbias, qkvb, N, 128, 384);

  // CSR by dst: hist -> scan -> rank (4B scatter) -> sequential fill
  hipMemsetAsync(pos, 0, (size_t)N * sizeof(int), stream);
  edge_hist<<<dim3(ge), blk, 0, stream>>>(ei, pos, E);
  deg_block_sum<<<dim3(nb), blk, 0, stream>>>(pos, bsum, N);
  scan_bsum<<<dim3(1), dim3(64), 0, stream>>>(bsum, offs + N, nb);
  deg_scan_write<<<dim3(nb), blk, 0, stream>>>(pos, bsum, offs, pos, N);
  edge_rank<<<dim3(ge), blk, 0, stream>>>(ei, pos, inv, E);
  csr_fill<<<dim3(ge), blk, 0, stream>>>(inv, ei, ea, eW, eb, csr_src, ebp, E);

  // fused attention aggregate (one wave per node, static)
  node_agg<<<dim3((N + 3) / 4), blk, 0, stream>>>(csr_src, offs, qkvb, ebp, aggb, N);

  // output projection fused with residual LN1 -> x1 (f32) + x1bf (bf16)
  gemm_ln<true><<<g128, blk, 0, stream>>>(aggb, oWt, ob, x, ln1_g, ln1_b, x1, x1bf, N, 128);

  // FFN
  gemm_mfma<true><<<gf1, blk, 0, stream>>>(x1bf, f1Wt, f1b, hbufb, N, 128, 512);
  ln_gelu512<<<dim3(N), blk, 0, stream>>>(hbufb, lnf_g, lnf_b, N);
  gemm_ln<false><<<g128, blk, 0, stream>>>(hbufb, f2Wt, f2b, x1, ln2_g, ln2_b, out, nullptr, N, 512);
}

// Round 8
// 315.637 us; speedup vs baseline: 1.1399x; 1.1399x over previous
//
#include <hip/hip_runtime.h>
#include <math.h>

#define LN_EPS 1e-5f

typedef __attribute__((ext_vector_type(8))) __bf16 bf16x8;
typedef __attribute__((ext_vector_type(4))) float f32x4;

__device__ inline float bf2f(unsigned short u) {
  union { unsigned int i; float f; } x; x.i = ((unsigned int)u) << 16; return x.f;
}
__device__ inline unsigned short f2bf(float f) {
  union { float f; unsigned int i; } x; x.f = f;
  unsigned int r = (x.i + 0x7FFFu + ((x.i >> 16) & 1u)) >> 16;   // RNE
  return (unsigned short)r;
}
__device__ inline void gload_lds16(const void* g, void* l) {
  __builtin_amdgcn_global_load_lds((const __attribute__((address_space(1))) void*)g,
                                   (__attribute__((address_space(3))) void*)l, 16, 0, 0);
}

// ---------------- f32 -> bf16 elementwise ----------------
__global__ __launch_bounds__(256)
void to_bf16(const float* __restrict__ in, unsigned short* __restrict__ outp, long n) {
  long i = ((long)blockIdx.x * 256 + threadIdx.x) * 4;
  if (i >= n) return;
  float4 v = *(const float4*)&in[i];
  ushort4 o = { f2bf(v.x), f2bf(v.y), f2bf(v.z), f2bf(v.w) };
  *(ushort4*)&outp[i] = o;
}

// ---------------- ALL weight transposes + qkv bias concat in ONE kernel ----------------
// tiles: [0,16) qW  [16,32) kW  [32,48) vW  [48,64) oW  [64,128) f1W(4x16)  [128,192) f2W(16x4)
// block 192: bias concat (384 floats)
struct WDesc { const float* W; unsigned short* Wt; int K, M, ntx; };  // ntx = K/32
__global__ __launch_bounds__(256)
void prep_weights(const float* qW, const float* kW, const float* vW, const float* oW,
                  const float* f1W, const float* f2W,
                  unsigned short* qkvWt, unsigned short* oWt,
                  unsigned short* f1Wt, unsigned short* f2Wt,
                  const float* qb, const float* kb, const float* vb, float* qkvbias) {
  const int t = blockIdx.x;
  if (t == 192) {
    int i = threadIdx.x;
    if (i < 128) { qkvbias[i] = qb[i]; qkvbias[128 + i] = kb[i]; }
    else if (i < 256) qkvbias[256 + (i - 128)] = vb[i - 128];
    return;
  }
  const float* W; unsigned short* Wt; int K, M, lt;
  if (t < 64)       { K = 128; M = 128; lt = t & 15;
    if (t < 16)      { W = qW; Wt = qkvWt; }
    else if (t < 32) { W = kW; Wt = qkvWt + 16384; }
    else if (t < 48) { W = vW; Wt = qkvWt + 32768; }
    else             { W = oW; Wt = oWt; } }
  else if (t < 128) { K = 128; M = 512; lt = t - 64; W = f1W; Wt = f1Wt; }
  else              { K = 512; M = 128; lt = t - 128; W = f2W; Wt = f2Wt; }
  const int ktiles = K >> 5;
  const int k0 = (lt % ktiles) * 32, m0 = (lt / ktiles) * 32;
  __shared__ float tb[32][33];
  const int tx = threadIdx.x & 31, ty = threadIdx.x >> 5;  // 32 x 8
#pragma unroll
  for (int i = 0; i < 32; i += 8)
    tb[ty + i][tx] = W[(size_t)(k0 + ty + i) * M + m0 + tx];
  __syncthreads();
#pragma unroll
  for (int i = 0; i < 32; i += 8)
    Wt[(size_t)(m0 + ty + i) * K + k0 + tx] = f2bf(tb[tx][ty + i]);
}

// ---------------- bf16 MFMA GEMM: C[N,M] = A[N,K] @ Wt[M,K]^T + bias ----------------
template<bool OBF>
__global__ __launch_bounds__(256)
void gemm_mfma(const unsigned short* __restrict__ A, const unsigned short* __restrict__ Wt,
               const float* __restrict__ bias, void* __restrict__ Cout,
               int Nr, int K, int M) {
  __shared__ __align__(16) unsigned short As[128 * 64];
  __shared__ __align__(16) unsigned short Bs[128 * 64];
  const int tid = threadIdx.x;
  const int bm = blockIdx.x * 128, bn = blockIdx.y * 128;
  const int lane = tid & 63;
  const int wr = (tid >> 6) >> 1, wc = (tid >> 6) & 1;
  f32x4 acc[4][4] = {};
  const int nkt = K >> 6;
  for (int kt = 0; kt < nkt; ++kt) {
#pragma unroll
    for (int i = 0; i < 4; ++i) {
      int c = tid + i * 256;
      int row = c >> 3;
      int j = (c & 7) ^ (row & 7);
      int ar = bm + row; ar = ar < Nr ? ar : Nr - 1;
      gload_lds16(A + (size_t)ar * K + kt * 64 + j * 8, As + (size_t)c * 8);
      gload_lds16(Wt + (size_t)(bn + row) * K + kt * 64 + j * 8, Bs + (size_t)c * 8);
    }
    __syncthreads();
#pragma unroll
    for (int ks = 0; ks < 2; ++ks) {
      bf16x8 af[4], bfr[4];
#pragma unroll
      for (int f = 0; f < 4; ++f) {
        int rowa = wr * 64 + f * 16 + (lane & 15);
        int ja = (ks * 4 + (lane >> 4)) ^ (rowa & 7);
        af[f] = *(const bf16x8*)(As + rowa * 64 + ja * 8);
        int rowb = wc * 64 + f * 16 + (lane & 15);
        int jb = (ks * 4 + (lane >> 4)) ^ (rowb & 7);
        bfr[f] = *(const bf16x8*)(Bs + rowb * 64 + jb * 8);
      }
#pragma unroll
      for (int fr = 0; fr < 4; ++fr)
#pragma unroll
        for (int fc = 0; fc < 4; ++fc)
          acc[fr][fc] = __builtin_amdgcn_mfma_f32_16x16x32_bf16(af[fr], bfr[fc], acc[fr][fc], 0, 0, 0);
    }
    __syncthreads();
  }
#pragma unroll
  for (int fr = 0; fr < 4; ++fr) {
#pragma unroll
    for (int j = 0; j < 4; ++j) {
      int row = bm + wr * 64 + fr * 16 + (lane >> 4) * 4 + j;
      if (row < Nr) {
#pragma unroll
        for (int fc = 0; fc < 4; ++fc) {
          int col = bn + wc * 64 + fc * 16 + (lane & 15);
          float v = acc[fr][fc][j] + bias[col];
          if (OBF) ((unsigned short*)Cout)[(size_t)row * M + col] = f2bf(v);
          else     ((float*)Cout)[(size_t)row * M + col] = v;
        }
      }
    }
  }
}

// ------- bf16 MFMA GEMM (M=128) fused with y = LN(res + A@Wt^T + bias) -------
// WF32: write f32 y;  WBF: write bf16 ybf;  RESBF: residual is bf16
template<bool WF32, bool WBF, bool RESBF>
__global__ __launch_bounds__(256)
void gemm_ln(const unsigned short* __restrict__ A, const unsigned short* __restrict__ Wt,
             const float* __restrict__ bias, const void* __restrict__ res,
             const float* __restrict__ g, const float* __restrict__ b,
             float* __restrict__ y, unsigned short* __restrict__ ybf, int Nr, int K) {
  __shared__ __align__(16) unsigned short As[128 * 64];
  __shared__ __align__(16) unsigned short Bs[128 * 64];
  __shared__ float pls[128][2], plss[128][2];
  const int tid = threadIdx.x;
  const int bm = blockIdx.x * 128;
  const int lane = tid & 63;
  const int wr = (tid >> 6) >> 1, wc = (tid >> 6) & 1;
  f32x4 acc[4][4] = {};
  const int nkt = K >> 6;
  for (int kt = 0; kt < nkt; ++kt) {
#pragma unroll
    for (int i = 0; i < 4; ++i) {
      int c = tid + i * 256;
      int row = c >> 3;
      int j = (c & 7) ^ (row & 7);
      int ar = bm + row; ar = ar < Nr ? ar : Nr - 1;
      gload_lds16(A + (size_t)ar * K + kt * 64 + j * 8, As + (size_t)c * 8);
      gload_lds16(Wt + (size_t)row * K + kt * 64 + j * 8, Bs + (size_t)c * 8);
    }
    __syncthreads();
#pragma unroll
    for (int ks = 0; ks < 2; ++ks) {
      bf16x8 af[4], bfr[4];
#pragma unroll
      for (int f = 0; f < 4; ++f) {
        int rowa = wr * 64 + f * 16 + (lane & 15);
        int ja = (ks * 4 + (lane >> 4)) ^ (rowa & 7);
        af[f] = *(const bf16x8*)(As + rowa * 64 + ja * 8);
        int rowb = wc * 64 + f * 16 + (lane & 15);
        int jb = (ks * 4 + (lane >> 4)) ^ (rowb & 7);
        bfr[f] = *(const bf16x8*)(Bs + rowb * 64 + jb * 8);
      }
#pragma unroll
      for (int fr = 0; fr < 4; ++fr)
#pragma unroll
        for (int fc = 0; fc < 4; ++fc)
          acc[fr][fc] = __builtin_amdgcn_mfma_f32_16x16x32_bf16(af[fr], bfr[fc], acc[fr][fc], 0, 0, 0);
    }
    __syncthreads();
  }
  // epilogue: val = acc + bias + res; per-row LN across both wc halves via LDS partials
#pragma unroll
  for (int fr = 0; fr < 4; ++fr) {
#pragma unroll
    for (int j = 0; j < 4; ++j) {
      const int rl = wr * 64 + fr * 16 + (lane >> 4) * 4 + j;
      const int row = bm + rl;
      const int rowc = row < Nr ? row : Nr - 1;
      float s = 0.f, ss = 0.f;
#pragma unroll
      for (int fc = 0; fc < 4; ++fc) {
        int col = wc * 64 + fc * 16 + (lane & 15);
        float rv = RESBF ? bf2f(((const unsigned short*)res)[(size_t)rowc * 128 + col])
                         : ((const float*)res)[(size_t)rowc * 128 + col];
        float val = acc[fr][fc][j] + bias[col] + rv;
        acc[fr][fc][j] = val;
        s += val; ss += val * val;
      }
      s += __shfl_xor(s, 1); ss += __shfl_xor(ss, 1);
      s += __shfl_xor(s, 2); ss += __shfl_xor(ss, 2);
      s += __shfl_xor(s, 4); ss += __shfl_xor(ss, 4);
      s += __shfl_xor(s, 8); ss += __shfl_xor(ss, 8);
      if ((lane & 15) == 0) { pls[rl][wc] = s; plss[rl][wc] = ss; }
    }
  }
  __syncthreads();
#pragma unroll
  for (int fr = 0; fr < 4; ++fr) {
#pragma unroll
    for (int j = 0; j < 4; ++j) {
      const int rl = wr * 64 + fr * 16 + (lane >> 4) * 4 + j;
      const int row = bm + rl;
      if (row >= Nr) continue;
      const float S = pls[rl][0] + pls[rl][1];
      const float SS = plss[rl][0] + plss[rl][1];
      const float mu = S * (1.f / 128.f);
      const float inv = rsqrtf(SS * (1.f / 128.f) - mu * mu + LN_EPS);
#pragma unroll
      for (int fc = 0; fc < 4; ++fc) {
        int col = wc * 64 + fc * 16 + (lane & 15);
        float o = (acc[fr][fc][j] - mu) * inv * g[col] + b[col];
        if (WF32) y[(size_t)row * 128 + col] = o;
        if (WBF)  ybf[(size_t)row * 128 + col] = f2bf(o);
      }
    }
  }
}

// ---------------- CSR build ----------------
__global__ __launch_bounds__(256)
void edge_hist(const int* __restrict__ ei, int* __restrict__ deg, int E) {
  int e = blockIdx.x * 256 + threadIdx.x;
  if (e < E) atomicAdd(&deg[ei[E + e]], 1);
}

__global__ __launch_bounds__(256)
void deg_block_sum(const int* __restrict__ deg, int* __restrict__ bsum, int N) {
  const int t = threadIdx.x;
  const int beg = blockIdx.x * 2048 + t * 8;
  int s = 0;
#pragma unroll
  for (int j = 0; j < 8; ++j) { int i = beg + j; if (i < N) s += deg[i]; }
#pragma unroll
  for (int off = 32; off; off >>= 1) s += __shfl_xor(s, off);
  __shared__ int ws[4];
  if ((t & 63) == 0) ws[t >> 6] = s;
  __syncthreads();
  if (t == 0) bsum[blockIdx.x] = ws[0] + ws[1] + ws[2] + ws[3];
}

__global__ __launch_bounds__(64)
void scan_bsum(int* __restrict__ bsum, int* __restrict__ offs_last, int nb) {
  const int t = threadIdx.x;
  int v = (t < nb) ? bsum[t] : 0;
  int inc = v;
#pragma unroll
  for (int off = 1; off < 64; off <<= 1) {
    int x = __shfl_up(inc, off);
    if (t >= off) inc += x;
  }
  if (t < nb) bsum[t] = inc - v;
  if (t == 63) *offs_last = inc;
}

__global__ __launch_bounds__(256)
void deg_scan_write(const int* __restrict__ deg, const int* __restrict__ bsum,
                    int* __restrict__ offs, int* __restrict__ pos, int N) {
  const int t = threadIdx.x;
  const int beg = blockIdx.x * 2048 + t * 8;
  int loc[8]; int T = 0;
#pragma unroll
  for (int j = 0; j < 8; ++j) { int i = beg + j; loc[j] = (i < N) ? deg[i] : 0; T += loc[j]; }
  int inc = T;
#pragma unroll
  for (int off = 1; off < 64; off <<= 1) {
    int x = __shfl_up(inc, off);
    if ((t & 63) >= off) inc += x;
  }
  __shared__ int ws[4];
  if ((t & 63) == 63) ws[t >> 6] = inc;
  __syncthreads();
  const int wid = t >> 6;
  int wbase = 0;
  for (int w = 0; w < wid; ++w) wbase += ws[w];
  int base = bsum[blockIdx.x] + wbase + inc - T;
#pragma unroll
  for (int j = 0; j < 8; ++j) {
    int i = beg + j;
    if (i < N) { offs[i] = base; pos[i] = base; base += loc[j]; }
  }
}

// scatter fused with edge-bias: ebp[p][h] = bf16( ea[e,:]@eW[:,h] + eb[h] )
__global__ __launch_bounds__(256)
void edge_scatter_bias(const int* __restrict__ ei, int* __restrict__ pos,
                       const float* __restrict__ ea, const float* __restrict__ eW,
                       const float* __restrict__ eb, int* __restrict__ csr_src,
                       unsigned short* __restrict__ ebp, int E) {
  __shared__ float ews[256];
  __shared__ float ebs[8];
  const int tid = threadIdx.x;
  if (tid < 256) ews[tid] = eW[tid];
  if (tid < 8) ebs[tid] = eb[tid];
  __syncthreads();
  int e = blockIdx.x * 256 + tid;
  if (e >= E) return;
  float bias[8];
#pragma unroll
  for (int h = 0; h < 8; ++h) bias[h] = ebs[h];
#pragma unroll
  for (int i4 = 0; i4 < 8; ++i4) {
    float4 a = *(const float4*)&ea[(size_t)e * 32 + i4 * 4];
    float av[4] = {a.x, a.y, a.z, a.w};
#pragma unroll
    for (int j = 0; j < 4; ++j)
#pragma unroll
      for (int h = 0; h < 8; ++h) bias[h] += av[j] * ews[(i4 * 4 + j) * 8 + h];
  }
  int d = ei[E + e];
  int p = atomicAdd(&pos[d], 1);
  csr_src[p] = ei[e];
  union { unsigned short us[8]; uint4 v; } pk;
#pragma unroll
  for (int h = 0; h < 8; ++h) pk.us[h] = f2bf(bias[h]);
  *(uint4*)&ebp[(size_t)p * 8] = pk.v;
}

// ---------------- fused per-node attention aggregate ----------------
// merged qkv[N][384] bf16 (q:0-127, k:128-255, v:256-383); one wave per node (static)
__global__ __launch_bounds__(256)
void node_agg(const int* __restrict__ csr_src, const int* __restrict__ offs,
              const unsigned short* __restrict__ qkv, const unsigned short* __restrict__ ebp,
              unsigned short* __restrict__ agg, int N) {
  const int wid = threadIdx.x >> 6, lane = threadIdx.x & 63;
  const int h = lane >> 3;
  const long n = (long)blockIdx.x * 4 + wid;
  if (n >= N) return;
  const int off = offs[n], end = offs[n + 1];
  const ushort2 kv2 = *(const ushort2*)&qkv[(size_t)n * 384 + 128 + lane * 2];
  const float k0 = bf2f(kv2.x), k1 = bf2f(kv2.y);
  float acc0 = 0.f, acc1 = 0.f, den = 0.f;
  int i = off;
  for (; i + 8 <= end; i += 8) {       // 8-wide: 16 independent q/v gathers in flight
    size_t bb[8];
#pragma unroll
    for (int u = 0; u < 8; ++u) bb[u] = (size_t)csr_src[i + u] * 384;
    ushort2 qv[8], vv[8];
#pragma unroll
    for (int u = 0; u < 8; ++u) qv[u] = *(const ushort2*)&qkv[bb[u] + lane * 2];
#pragma unroll
    for (int u = 0; u < 8; ++u) vv[u] = *(const ushort2*)&qkv[bb[u] + 256 + lane * 2];
    float ebv[8];
#pragma unroll
    for (int u = 0; u < 8; ++u) ebv[u] = bf2f(ebp[(size_t)(i + u) * 8 + h]);
    float p[8];
#pragma unroll
    for (int u = 0; u < 8; ++u) p[u] = bf2f(qv[u].x) * k0 + bf2f(qv[u].y) * k1;
#pragma unroll
    for (int u = 0; u < 8; ++u) {
      p[u] += __shfl_xor(p[u], 1);
      p[u] += __shfl_xor(p[u], 2);
      p[u] += __shfl_xor(p[u], 4);
    }
#pragma unroll
    for (int u = 0; u < 8; ++u) {
      const float ex = __expf(p[u] * 0.25f + ebv[u]);
      den += ex;
      acc0 += bf2f(vv[u].x) * ex;
      acc1 += bf2f(vv[u].y) * ex;
    }
  }
  for (; i + 4 <= end; i += 4) {
    size_t bb[4];
#pragma unroll
    for (int u = 0; u < 4; ++u) bb[u] = (size_t)csr_src[i + u] * 384;
    ushort2 qv[4], vv[4];
#pragma unroll
    for (int u = 0; u < 4; ++u) qv[u] = *(const ushort2*)&qkv[bb[u] + lane * 2];
#pragma unroll
    for (int u = 0; u < 4; ++u) vv[u] = *(const ushort2*)&qkv[bb[u] + 256 + lane * 2];
    float ebv[4];
#pragma unroll
    for (int u = 0; u < 4; ++u) ebv[u] = bf2f(ebp[(size_t)(i + u) * 8 + h]);
    float p[4];
#pragma unroll
    for (int u = 0; u < 4; ++u) p[u] = bf2f(qv[u].x) * k0 + bf2f(qv[u].y) * k1;
#pragma unroll
    for (int u = 0; u < 4; ++u) {
      p[u] += __shfl_xor(p[u], 1);
      p[u] += __shfl_xor(p[u], 2);
      p[u] += __shfl_xor(p[u], 4);
    }
#pragma unroll
    for (int u = 0; u < 4; ++u) {
      const float ex = __expf(p[u] * 0.25f + ebv[u]);
      den += ex;
      acc0 += bf2f(vv[u].x) * ex;
      acc1 += bf2f(vv[u].y) * ex;
    }
  }
  for (; i < end; ++i) {
    const size_t b0 = (size_t)csr_src[i] * 384;
    const ushort2 qa = *(const ushort2*)&qkv[b0 + lane * 2];
    const ushort2 va = *(const ushort2*)&qkv[b0 + 256 + lane * 2];
    float p = bf2f(qa.x) * k0 + bf2f(qa.y) * k1;
    p += __shfl_xor(p, 1);
    p += __shfl_xor(p, 2);
    p += __shfl_xor(p, 4);
    const float ex = __expf(p * 0.25f + bf2f(ebp[(size_t)i * 8 + h]));
    den += ex;
    acc0 += bf2f(va.x) * ex;
    acc1 += bf2f(va.y) * ex;
  }
  const float r = 1.f / fmaxf(den, 1e-8f);
  ushort2 o; o.x = f2bf(acc0 * r); o.y = f2bf(acc1 * r);
  *(ushort2*)&agg[(size_t)n * 128 + lane * 2] = o;
}

// ---------------- in-place LN(row of 512) -> exact GELU, bf16 ----------------
__global__ __launch_bounds__(256)
void ln_gelu512(unsigned short* __restrict__ hbuf, const float* __restrict__ g,
                const float* __restrict__ b, int Nr) {
  __shared__ float rs[4], rss[4];
  const long row = blockIdx.x;
  const int tid = threadIdx.x;
  ushort2 u = *(ushort2*)&hbuf[row * 512 + tid * 2];
  float v0 = bf2f(u.x), v1 = bf2f(u.y);
  float s = v0 + v1, ss = v0 * v0 + v1 * v1;
#pragma unroll
  for (int off = 32; off; off >>= 1) { s += __shfl_xor(s, off); ss += __shfl_xor(ss, off); }
  const int wid = tid >> 6, lane = tid & 63;
  if (lane == 0) { rs[wid] = s; rss[wid] = ss; }
  __syncthreads();
  s = rs[0] + rs[1] + rs[2] + rs[3];
  ss = rss[0] + rss[1] + rss[2] + rss[3];
  const float mu = s * (1.f / 512.f);
  const float inv = rsqrtf(ss * (1.f / 512.f) - mu * mu + LN_EPS);
  float t0 = (v0 - mu) * inv * g[tid * 2] + b[tid * 2];
  float t1 = (v1 - mu) * inv * g[tid * 2 + 1] + b[tid * 2 + 1];
  t0 = 0.5f * t0 * (1.f + erff(t0 * 0.70710678118654752f));
  t1 = 0.5f * t1 * (1.f + erff(t1 * 0.70710678118654752f));
  ushort2 o; o.x = f2bf(t0); o.y = f2bf(t1);
  *(ushort2*)&hbuf[row * 512 + tid * 2] = o;
}

extern "C" void kernel_launch(void* const* d_in, const int* in_sizes, int n_in,
                              void* d_out, int out_size, void* d_ws, size_t ws_size,
                              hipStream_t stream) {
  const float* x   = (const float*)d_in[0];
  const int*   ei  = (const int*)d_in[1];
  const float* ea  = (const float*)d_in[2];
  const float* qW  = (const float*)d_in[3];
  const float* qbi = (const float*)d_in[4];
  const float* kW  = (const float*)d_in[5];
  const float* kbi = (const float*)d_in[6];
  const float* vW  = (const float*)d_in[7];
  const float* vbi = (const float*)d_in[8];
  const float* eW  = (const float*)d_in[9];
  const float* eb  = (const float*)d_in[10];
  const float* oW  = (const float*)d_in[11];
  const float* ob  = (const float*)d_in[12];
  const float* ln1_g = (const float*)d_in[13];
  const float* ln1_b = (const float*)d_in[14];
  const float* f1W = (const float*)d_in[15];
  const float* f1b = (const float*)d_in[16];
  const float* lnf_g = (const float*)d_in[17];
  const float* lnf_b = (const float*)d_in[18];
  const float* f2W = (const float*)d_in[19];
  const float* f2b = (const float*)d_in[20];
  const float* ln2_g = (const float*)d_in[21];
  const float* ln2_b = (const float*)d_in[22];
  float* out = (float*)d_out;

  const int N = in_sizes[0] / 128;
  const int E = in_sizes[1] / 2;
  const size_t NH = (size_t)N * 128;   // 6.4M floats

  // workspace (float units), lifetime-overlapped:
  //  [0, .5NH)      xbf bf16  -> x1bf bf16 (after QKV gemm)
  //  [.5NH, 2NH)    qkv bf16 [N][384]  \__ hbuf bf16 [N][512] overlays [.5NH, 2.5NH)
  //  [2NH, 2.5NH)   ebp bf16 [E][8]    /    (qkv+ebp dead before f1 writes hbuf)
  //  [2.5NH, 3NH)   aggb bf16
  //  [4NH, ...)     ints: csr_src E, offs N+1, pos N, bsum; then bf16 weights + bias
  float* F = (float*)d_ws;
  unsigned short* xbf   = (unsigned short*)F;
  unsigned short* qkvb  = (unsigned short*)(F + NH / 2);
  unsigned short* ebp   = (unsigned short*)(F + 2 * NH);
  unsigned short* aggb  = (unsigned short*)(F + 2 * NH + NH / 2);
  unsigned short* x1bf  = xbf;
  unsigned short* hbufb = (unsigned short*)(F + NH / 2);
  int* ib      = (int*)(F + 4 * NH);
  int* csr_src = ib;
  int* offs    = ib + E;
  int* pos     = ib + E + N + 1;
  int* bsum    = ib + E + 2 * N + 1;
  unsigned short* wt = (unsigned short*)(ib + E + 2 * N + 128);
  unsigned short* qkvWt = wt;            // 384x128
  unsigned short* oWt   = wt + 49152;    // 128x128
  unsigned short* f1Wt  = wt + 65536;    // 512x128
  unsigned short* f2Wt  = wt + 131072;   // 128x512
  float* qkvbias = (float*)(wt + 196608);

  dim3 blk(256);
  dim3 gqkv((N + 127) / 128, 3);
  dim3 g128((N + 127) / 128, 1);
  dim3 gf1((N + 127) / 128, 4);
  const int nb = (N + 2047) / 2048;
  const int ge = (E + 255) / 256;

  // converts + ALL weight prep in one launch
  to_bf16<<<dim3((int)((NH / 4 + 255) / 256)), blk, 0, stream>>>(x, xbf, (long)NH);
  prep_weights<<<dim3(193), blk, 0, stream>>>(qW, kW, vW, oW, f1W, f2W,
                                              qkvWt, oWt, f1Wt, f2Wt,
                                              qbi, kbi, vbi, qkvbias);

  // merged QKV projection -> qkv[N][384] bf16
  gemm_mfma<true><<<gqkv, blk, 0, stream>>>(xbf, qkvWt, qkvbias, qkvb, N, 128, 384);

  // CSR by dst + fused edge-bias scatter (ebp bf16 in CSR order)
  hipMemsetAsync(pos, 0, (size_t)N * sizeof(int), stream);
  edge_hist<<<dim3(ge), blk, 0, stream>>>(ei, pos, E);
  deg_block_sum<<<dim3(nb), blk, 0, stream>>>(pos, bsum, N);
  scan_bsum<<<dim3(1), dim3(64), 0, stream>>>(bsum, offs + N, nb);
  deg_scan_write<<<dim3(nb), blk, 0, stream>>>(pos, bsum, offs, pos, N);
  edge_scatter_bias<<<dim3(ge), blk, 0, stream>>>(ei, pos, ea, eW, eb, csr_src, ebp, E);

  // fused attention aggregate (one wave per node, static)
  node_agg<<<dim3((N + 3) / 4), blk, 0, stream>>>(csr_src, offs, qkvb, ebp, aggb, N);

  // output projection fused with residual LN1 -> x1bf (bf16 only)
  gemm_ln<false, true, false><<<g128, blk, 0, stream>>>(aggb, oWt, ob, x,
                                                        ln1_g, ln1_b, nullptr, x1bf, N, 128);

  // FFN
  gemm_mfma<true><<<gf1, blk, 0, stream>>>(x1bf, f1Wt, f1b, hbufb, N, 128, 512);
  ln_gelu512<<<dim3(N), blk, 0, stream>>>(hbufb, lnf_g, lnf_b, N);
  gemm_ln<true, false, true><<<g128, blk, 0, stream>>>(hbufb, f2Wt, f2b, x1bf,
                                                       ln2_g, ln2_b, out, nullptr, N, 512);
}